// Round 2
// baseline (259.277 us; speedup 1.0000x reference)
//
#include <hip/hip_runtime.h>
#include <hip/hip_bf16.h>

// Problem constants
#define B_   2
#define N_   512
#define M_   512
#define D_   128    // Dq = Dk = Dv
#define DE_  64
#define H_   8
#define O_   32
#define OUT_ 128
#define DKE_ 192    // Dk + De
#define MP_  516    // padded M for attn_s rows

typedef unsigned short u16;
typedef unsigned int   u32;
typedef short bf16x8 __attribute__((ext_vector_type(8)));
typedef float floatx4 __attribute__((ext_vector_type(4)));

__device__ __forceinline__ u32 pk2bf(float a, float b) {
    __hip_bfloat162 h = __float22bfloat162_rn(make_float2(a, b));
    return *reinterpret_cast<u32*>(&h);
}
__device__ __forceinline__ u16 f2bf(float a) {
    __hip_bfloat16 h = __float2bfloat16(a);
    return *reinterpret_cast<u16*>(&h);
}
__device__ __forceinline__ float bf2f(u16 x) {
    return __uint_as_float(((u32)x) << 16);
}
// pack 8 fp32 (two float4) -> bf16x8 fragment
__device__ __forceinline__ bf16x8 cvt8(const float4 a, const float4 b) {
    union { u32 u[4]; bf16x8 v; } r;
    r.u[0] = pk2bf(a.x, a.y); r.u[1] = pk2bf(a.z, a.w);
    r.u[2] = pk2bf(b.x, b.y); r.u[3] = pk2bf(b.z, b.w);
    return r.v;
}

// ---------------------------------------------------------------------------
// k_proj, grid = 192 x 256 threads (qE moved into k_attn prologue).
// Blocks 0..127   : per 8 (b,m) rows -> vP bf16 [b][m>>3][col=h*32+o][m&7]
// Blocks 128..191 : keyF: key in bf16 MFMA-B-fragment order
//                   keyF[b][tl][kk][lane][8], lane=(q<<4)|br,
//                   element j = key[b][tl*16+br][kk*32+q*8+j]
// ---------------------------------------------------------------------------
__global__ __launch_bounds__(256) void k_proj(
    const float* __restrict__ value, const float* __restrict__ Wv,
    const float* __restrict__ key,
    u16* __restrict__ vP, u16* __restrict__ keyF)
{
    const int t = threadIdx.x;
    __shared__ float Xs[8][D_];

    if (blockIdx.x < 128) {
        const int r0 = blockIdx.x * 8;                  // global (b,m) row
        reinterpret_cast<float4*>(&Xs[0][0])[t] =
            reinterpret_cast<const float4*>(value + (size_t)r0 * D_)[t];
        __syncthreads();

        float acc[8] = {0,0,0,0,0,0,0,0};
        const float* wcol = Wv + (t >> 5) * (D_ * O_) + (t & 31);
        for (int k = 0; k < D_; k += 4) {
            const float w0 = wcol[(k+0) * O_];
            const float w1 = wcol[(k+1) * O_];
            const float w2 = wcol[(k+2) * O_];
            const float w3 = wcol[(k+3) * O_];
#pragma unroll
            for (int r = 0; r < 8; ++r) {
                const float4 x = *reinterpret_cast<const float4*>(&Xs[r][k]);
                acc[r] += x.x * w0 + x.y * w1 + x.z * w2 + x.w * w3;
            }
        }
        // PV-coalesced bf16 write: vP[b][m0>>3][col=t][0..7] as one 16 B store
        const int bb = r0 >> 9, m0 = r0 & 511;
        union { u32 u[4]; uint4 q; } pk;
        pk.u[0] = pk2bf(acc[0], acc[1]);
        pk.u[1] = pk2bf(acc[2], acc[3]);
        pk.u[2] = pk2bf(acc[4], acc[5]);
        pk.u[3] = pk2bf(acc[6], acc[7]);
        *reinterpret_cast<uint4*>(
            vP + ((((size_t)bb * 64) + (m0 >> 3)) * 256 + t) * 8) = pk.q;
    } else {
        // keyF builder: one block per (b, m-tile)
        const int kb = blockIdx.x - 128;                // 0..63
        const int bb = kb >> 5, tl = kb & 31;
        const int kk = t >> 6, l = t & 63;
        const int br = l & 15, q = l >> 4;
        const float* src = key + ((size_t)bb * M_ + tl * 16 + br) * D_ + kk * 32 + q * 8;
        const float4 f0 = *reinterpret_cast<const float4*>(src);
        const float4 f1 = *reinterpret_cast<const float4*>(src + 4);
        union { bf16x8 v; uint4 u; } r;
        r.v = cvt8(f0, f1);
        *reinterpret_cast<uint4*>(
            keyF + ((((size_t)bb * 32 + tl) * 4 + kk) * 64 + l) * 8) = r.u;
    }
}

// ---------------------------------------------------------------------------
// k_attn: one block per (b, n-pair). 512 threads = 8 waves, 2 blocks/CU.
//  - prologue computes qE for both n inline (query*Wq -> fold Wk), overlaid
//    on attn_s LDS; first edge tile prefetched before it to hide HBM latency.
//  - packed-A MFMA: A rows 0-7 = n0 heads, 8-15 = n1 heads. 4 key MFMAs
//    shared by both n (keyF fragments n-invariant); 2+2 edge MFMAs with
//    half-zero A operands accumulate into the same acc.
//  - edge staged to fragment-layout LDS with bank swizzle g ^= y<<1
//    (write 8B/lane and read b128 both hit the minimum bank spread).
//  - PV: one vP pass feeds both n's accumulators (halves vP L2 traffic).
// ---------------------------------------------------------------------------
__global__ __launch_bounds__(512, 4) void k_attn(
    const float* __restrict__ query, const float* __restrict__ Wq,
    const float* __restrict__ Wk,
    const float* __restrict__ edge,
    const u16* __restrict__ vP, const u16* __restrict__ keyF,
    const float* __restrict__ Wp, const float* __restrict__ bias,
    float* __restrict__ out)
{
    const int pr   = blockIdx.x;          // pair index: n0 = 2*pr
    const int idx0 = pr * 2;              // global row b*N + n0
    const int b    = pr >> 8;
    const int t    = threadIdx.x;
    const int lane = t & 63;
    const int wv   = t >> 6;              // 0..7

    __shared__ __attribute__((aligned(16))) float attn_s[2][H_][MP_]; // 33 KB
    __shared__ __attribute__((aligned(16))) u16 elds[8][2][2048];     // 32 KB
    __shared__ float mh_s[2][2][256];                                 // 4 KB
    __shared__ float part_s[2][2][OUT_];                              // 2 KB

    // prologue scratch overlaid on attn_s (dead until logits writes begin)
    float* Xq   = &attn_s[0][0][0];         // [2][128] query rows
    float* qh_s = Xq + 256;                 // [2][256] q-proj
    u16*  qE_l  = (u16*)(qh_s + 512);       // [2][1536] folded qE (bf16)

    // ---- early edge prefetch: first tile per wave, both n ----
    const float* eb0 = edge + (size_t)idx0 * (M_ * DE_);
    const float* eb1 = eb0 + (M_ * DE_);
    float4 ef0[4], ef1[4];
    {
        const float* tb0 = eb0 + (size_t)wv * 1024;
        const float* tb1 = eb1 + (size_t)wv * 1024;
#pragma unroll
        for (int i = 0; i < 4; ++i) {
            ef0[i] = reinterpret_cast<const float4*>(tb0)[i * 64 + lane];
            ef1[i] = reinterpret_cast<const float4*>(tb1)[i * 64 + lane];
        }
    }

    // ---- prologue: qh = (query . Wq) * 1/sqrt(O) ----
    if (t < 64)
        reinterpret_cast<float4*>(Xq)[t] =
            reinterpret_cast<const float4*>(query + (size_t)idx0 * D_)[t];
    __syncthreads();
    {
        const int n = t >> 8, col = t & 255;
        const float* wcol = Wq + (col >> 5) * (D_ * O_) + (col & 31);
        const float* x = Xq + n * D_;
        float acc = 0.f;
        for (int k = 0; k < D_; k += 4) {
            const float4 xv = *reinterpret_cast<const float4*>(x + k);
            acc += xv.x * wcol[(k+0) * O_] + xv.y * wcol[(k+1) * O_]
                 + xv.z * wcol[(k+2) * O_] + xv.w * wcol[(k+3) * O_];
        }
        qh_s[n * 256 + col] = acc * 0.17677669529663687f;
    }
    __syncthreads();
    // ---- fold Wk: qE[n][hj] = sum_o qh[n][h*32+o] * Wk[hj][o] ----
#pragma unroll
    for (int s = 0; s < 3; ++s) {
        const int hj = t + 512 * s;       // 0..1535
        const int h  = hj / DKE_;
        float w[O_];
#pragma unroll
        for (int i = 0; i < O_ / 4; ++i) {
            const float4 x = reinterpret_cast<const float4*>(Wk + (size_t)hj * O_)[i];
            w[4*i] = x.x; w[4*i+1] = x.y; w[4*i+2] = x.z; w[4*i+3] = x.w;
        }
#pragma unroll
        for (int n = 0; n < 2; ++n) {
            const float* qrow = qh_s + n * 256 + h * O_;
            float a = 0.f;
#pragma unroll
            for (int i = 0; i < O_ / 4; ++i) {
                const float4 qx = *reinterpret_cast<const float4*>(qrow + 4*i);
                a += qx.x * w[4*i] + qx.y * w[4*i+1] + qx.z * w[4*i+2] + qx.w * w[4*i+3];
            }
            qE_l[n * 1536 + hj] = f2bf(a);
        }
    }
    __syncthreads();

    // ---- A fragments (packed 2n): rows 0-7 = n0 heads, 8-15 = n1 heads ----
    const int br = lane & 15;             // A row / C col (m)
    const int q  = lane >> 4;             // k-quad
    const int nsel = br >> 3, hsel = br & 7;
    bf16x8 afr_k[4], afr_e0[2], afr_e1[2];
    {
        const u16* ab = qE_l + nsel * 1536 + hsel * DKE_;
#pragma unroll
        for (int kk = 0; kk < 4; ++kk)
            afr_k[kk] = *reinterpret_cast<const bf16x8*>(ab + kk * 32 + q * 8);
        const bf16x8 ze = {0,0,0,0,0,0,0,0};
#pragma unroll
        for (int kk = 0; kk < 2; ++kk) {
            const bf16x8 fr = *reinterpret_cast<const bf16x8*>(ab + 128 + kk * 32 + q * 8);
            afr_e0[kk] = nsel ? ze : fr;
            afr_e1[kk] = nsel ? fr : ze;
        }
    }
    __syncthreads();   // qE_l alias region must be dead before attn_s writes

    const u16* kfb = keyF + (size_t)b * (32 * 4 * 64 * 8);

    // ---- logits: each wave 4 m-tiles, both n per tile ----
    for (int it = 0; it < 4; ++it) {
        const int tl = it * 8 + wv;
        // stage both edge tiles into fragment-layout LDS (bank-swizzled)
#pragma unroll
        for (int i = 0; i < 4; ++i) {
            const int c = i * 64 + lane;
            const int row = c >> 4, col4 = c & 15;
            const int kk = col4 >> 3, y = (col4 >> 1) & 3;
            const int g = (kk * 64 + y * 16 + row) ^ (y << 1);
            const int off = g * 8 + (col4 & 1) * 4;
            uint2 p0, p1;
            p0.x = pk2bf(ef0[i].x, ef0[i].y); p0.y = pk2bf(ef0[i].z, ef0[i].w);
            p1.x = pk2bf(ef1[i].x, ef1[i].y); p1.y = pk2bf(ef1[i].z, ef1[i].w);
            *reinterpret_cast<uint2*>(&elds[wv][0][off]) = p0;
            *reinterpret_cast<uint2*>(&elds[wv][1][off]) = p1;
        }
        // prefetch next tile pair (coalesced)
        if (it < 3) {
            const float* tb0 = eb0 + (size_t)(tl + 8) * 1024;
            const float* tb1 = eb1 + (size_t)(tl + 8) * 1024;
#pragma unroll
            for (int i = 0; i < 4; ++i) {
                ef0[i] = reinterpret_cast<const float4*>(tb0)[i * 64 + lane];
                ef1[i] = reinterpret_cast<const float4*>(tb1)[i * 64 + lane];
            }
        }
        // key MFMAs: shared by both n (packed A)
        floatx4 acc = {0.f, 0.f, 0.f, 0.f};
        const u16* kf = kfb + (size_t)tl * 2048 + lane * 8;
#pragma unroll
        for (int kk = 0; kk < 4; ++kk) {
            const bf16x8 bfr = *reinterpret_cast<const bf16x8*>(kf + kk * 512);
            acc = __builtin_amdgcn_mfma_f32_16x16x32_bf16(afr_k[kk], bfr, acc, 0, 0, 0);
        }
        // edge MFMAs (half-zero A operands, same acc)
        const int swz = ((lane >> 4) & 3) << 1;
#pragma unroll
        for (int kk = 0; kk < 2; ++kk) {
            const int g = (kk * 64 + lane) ^ swz;
            const bf16x8 b0 = *reinterpret_cast<const bf16x8*>(&elds[wv][0][g * 8]);
            acc = __builtin_amdgcn_mfma_f32_16x16x32_bf16(afr_e0[kk], b0, acc, 0, 0, 0);
        }
#pragma unroll
        for (int kk = 0; kk < 2; ++kk) {
            const int g = (kk * 64 + lane) ^ swz;
            const bf16x8 b1 = *reinterpret_cast<const bf16x8*>(&elds[wv][1][g * 8]);
            acc = __builtin_amdgcn_mfma_f32_16x16x32_bf16(afr_e1[kk], b1, acc, 0, 0, 0);
        }
        // C: col=br (m), row=q*4+i -> n = row>>3, h = row&7. All lanes write.
#pragma unroll
        for (int i = 0; i < 4; ++i) {
            const int rr = q * 4 + i;
            attn_s[rr >> 3][rr & 7][tl * 16 + br] = acc[i];
        }
    }
    __syncthreads();

    // ---- softmax over m: 16 rows = (n,h), 32 lanes per row ----
    {
        const int r = t >> 5, ml = t & 31;
        const int n = r >> 3, h = r & 7;
        float mx = -3.4e38f;
#pragma unroll 2
        for (int j = 0; j < 16; ++j) mx = fmaxf(mx, attn_s[n][h][ml + 32 * j]);
#pragma unroll
        for (int mask = 16; mask >= 1; mask >>= 1) mx = fmaxf(mx, __shfl_xor(mx, mask, 64));
        float sum = 0.f;
#pragma unroll 2
        for (int j = 0; j < 16; ++j) {
            const int m = ml + 32 * j;
            const float p = __expf(attn_s[n][h][m] - mx);
            attn_s[n][h][m] = p;
            sum += p;
        }
#pragma unroll
        for (int mask = 16; mask >= 1; mask >>= 1) sum += __shfl_xor(sum, mask, 64);
        const float inv = 1.f / sum;
#pragma unroll 2
        for (int j = 0; j < 16; ++j) attn_s[n][h][ml + 32 * j] *= inv;
    }
    __syncthreads();

    // ---- PV: col tt=(h,o), m split in halves; one vP pass feeds BOTH n ----
    {
        const int tt = t & 255, half = t >> 8, hh = tt >> 5;
        const u16* vb = vP + (size_t)b * (64 * 256 * 8)
                      + ((size_t)(half * 32) * 256 + tt) * 8;
        const int mbase = half * 256;
        float a00 = 0.f, a01 = 0.f, a10 = 0.f, a11 = 0.f;
#pragma unroll 4
        for (int j = 0; j < 32; ++j) {
            const bf16x8 v8 = *reinterpret_cast<const bf16x8*>(vb + (size_t)j * 2048);
            const int m0 = mbase + j * 8;
            const float4 w00 = *reinterpret_cast<const float4*>(&attn_s[0][hh][m0]);
            const float4 w01 = *reinterpret_cast<const float4*>(&attn_s[0][hh][m0 + 4]);
            const float4 w10 = *reinterpret_cast<const float4*>(&attn_s[1][hh][m0]);
            const float4 w11 = *reinterpret_cast<const float4*>(&attn_s[1][hh][m0 + 4]);
            const float v0 = bf2f((u16)v8[0]), v1 = bf2f((u16)v8[1]);
            const float v2 = bf2f((u16)v8[2]), v3 = bf2f((u16)v8[3]);
            const float v4 = bf2f((u16)v8[4]), v5 = bf2f((u16)v8[5]);
            const float v6 = bf2f((u16)v8[6]), v7 = bf2f((u16)v8[7]);
            a00 += w00.x * v0 + w00.y * v1 + w00.z * v2 + w00.w * v3;
            a01 += w01.x * v4 + w01.y * v5 + w01.z * v6 + w01.w * v7;
            a10 += w10.x * v0 + w10.y * v1 + w10.z * v2 + w10.w * v3;
            a11 += w11.x * v4 + w11.y * v5 + w11.z * v6 + w11.w * v7;
        }
        mh_s[0][half][tt] = a00 + a01;
        mh_s[1][half][tt] = a10 + a11;
    }
    __syncthreads();

    // ---- out[n][c] = bias[c] + sum_j mh[n][j] * Wp[j*128 + c] ----
    {
        const int n = t >> 8, hseg = (t >> 7) & 1, c = t & 127;
        const int j0 = hseg * 128;
        float acc = 0.f;
#pragma unroll 8
        for (int jj = 0; jj < 128; ++jj) {
            const int j = j0 + jj;
            acc += (mh_s[n][0][j] + mh_s[n][1][j]) * Wp[(size_t)j * OUT_ + c];
        }
        part_s[n][hseg][c] = acc;
    }
    __syncthreads();
    if (t < 256) {
        const int n = t >> 7, c = t & 127;
        out[(size_t)(idx0 + n) * OUT_ + c] = part_s[n][0][c] + part_s[n][1][c] + bias[c];
    }
}

// ---------------------------------------------------------------------------
extern "C" void kernel_launch(void* const* d_in, const int* in_sizes, int n_in,
                              void* d_out, int out_size, void* d_ws, size_t ws_size,
                              hipStream_t stream)
{
    const float* query = (const float*)d_in[0];   // [B,N,128]
    const float* key   = (const float*)d_in[1];   // [B,M,128]
    const float* value = (const float*)d_in[2];   // [B,M,128]
    const float* edge  = (const float*)d_in[3];   // [B,N,M,64]
    const float* Wq    = (const float*)d_in[4];   // [8,128,32]
    const float* Wk    = (const float*)d_in[5];   // [8,192,32]
    const float* Wv    = (const float*)d_in[6];   // [8,128,32]
    const float* Wp    = (const float*)d_in[7];   // [8,32,128]
    const float* bias  = (const float*)d_in[8];   // [128]
    float* out = (float*)d_out;                   // [B,N,128] fp32

    u16* vP_ws = (u16*)d_ws;                                  // 2*64*256*8*2 = 512 KB
    u16* kF_ws = vP_ws + (size_t)B_ * 64 * 256 * 8;           // 2*32*4*64*8*2 = 256 KB

    k_proj<<<192, 256, 0, stream>>>(value, Wv, key, vP_ws, kF_ws);
    k_attn<<<512, 512, 0, stream>>>(query, Wq, Wk, edge, vP_ws, kF_ws, Wp, bias, out);
}

// Round 3
// 246.969 us; speedup vs baseline: 1.0498x; 1.0498x over previous
//
#include <hip/hip_runtime.h>
#include <hip/hip_bf16.h>

// Problem constants
#define B_   2
#define N_   512
#define M_   512
#define D_   128    // Dq = Dk = Dv
#define DE_  64
#define H_   8
#define O_   32
#define OUT_ 128
#define DKE_ 192    // Dk + De
#define MP_  516    // padded M for attn_s rows

typedef unsigned short u16;
typedef unsigned int   u32;
typedef short bf16x8 __attribute__((ext_vector_type(8)));
typedef float floatx4 __attribute__((ext_vector_type(4)));

__device__ __forceinline__ u32 pk2bf(float a, float b) {
    __hip_bfloat162 h = __float22bfloat162_rn(make_float2(a, b));
    return *reinterpret_cast<u32*>(&h);
}
__device__ __forceinline__ u16 f2bf(float a) {
    __hip_bfloat16 h = __float2bfloat16(a);
    return *reinterpret_cast<u16*>(&h);
}
// pack 8 fp32 (two float4) -> bf16x8 fragment
__device__ __forceinline__ bf16x8 cvt8(const float4 a, const float4 b) {
    union { u32 u[4]; bf16x8 v; } r;
    r.u[0] = pk2bf(a.x, a.y); r.u[1] = pk2bf(a.z, a.w);
    r.u[2] = pk2bf(b.x, b.y); r.u[3] = pk2bf(b.z, b.w);
    return r.v;
}

// ---------------------------------------------------------------------------
// k_proj, grid = 192 x 256 threads.
// Blocks 0..127   : per 8 (b,m) rows -> vP bf16 [b][m>>3][col=h*32+o][m&7]
// Blocks 128..191 : keyF: key in bf16 MFMA-B-fragment order
//                   keyF[b][tl][kk][lane][8], lane=(q<<4)|br,
//                   element j = key[b][tl*16+br][kk*32+q*8+j]
// ---------------------------------------------------------------------------
__global__ __launch_bounds__(256) void k_proj(
    const float* __restrict__ value, const float* __restrict__ Wv,
    const float* __restrict__ key,
    u16* __restrict__ vP, u16* __restrict__ keyF)
{
    const int t = threadIdx.x;
    __shared__ float Xs[8][D_];

    if (blockIdx.x < 128) {
        const int r0 = blockIdx.x * 8;                  // global (b,m) row
        reinterpret_cast<float4*>(&Xs[0][0])[t] =
            reinterpret_cast<const float4*>(value + (size_t)r0 * D_)[t];
        __syncthreads();

        float acc[8] = {0,0,0,0,0,0,0,0};
        const float* wcol = Wv + (t >> 5) * (D_ * O_) + (t & 31);
        for (int k = 0; k < D_; k += 4) {
            const float w0 = wcol[(k+0) * O_];
            const float w1 = wcol[(k+1) * O_];
            const float w2 = wcol[(k+2) * O_];
            const float w3 = wcol[(k+3) * O_];
#pragma unroll
            for (int r = 0; r < 8; ++r) {
                const float4 x = *reinterpret_cast<const float4*>(&Xs[r][k]);
                acc[r] += x.x * w0 + x.y * w1 + x.z * w2 + x.w * w3;
            }
        }
        // PV-coalesced bf16 write: vP[b][m0>>3][col=t][0..7] as one 16 B store
        const int bb = r0 >> 9, m0 = r0 & 511;
        union { u32 u[4]; uint4 q; } pk;
        pk.u[0] = pk2bf(acc[0], acc[1]);
        pk.u[1] = pk2bf(acc[2], acc[3]);
        pk.u[2] = pk2bf(acc[4], acc[5]);
        pk.u[3] = pk2bf(acc[6], acc[7]);
        *reinterpret_cast<uint4*>(
            vP + ((((size_t)bb * 64) + (m0 >> 3)) * 256 + t) * 8) = pk.q;
    } else {
        // keyF builder: one block per (b, m-tile)
        const int kb = blockIdx.x - 128;                // 0..63
        const int bb = kb >> 5, tl = kb & 31;
        const int kk = t >> 6, l = t & 63;
        const int br = l & 15, q = l >> 4;
        const float* src = key + ((size_t)bb * M_ + tl * 16 + br) * D_ + kk * 32 + q * 8;
        const float4 f0 = *reinterpret_cast<const float4*>(src);
        const float4 f1 = *reinterpret_cast<const float4*>(src + 4);
        union { bf16x8 v; uint4 u; } r;
        r.v = cvt8(f0, f1);
        *reinterpret_cast<uint4*>(
            keyF + ((((size_t)bb * 32 + tl) * 4 + kk) * 64 + l) * 8) = r.u;
    }
}

// ---------------------------------------------------------------------------
// k_attn: one block per (b, n-pair). 512 threads = 8 waves, 2 blocks/CU
// (LDS 69.3 KB). Packed-A MFMA: rows 0-7 = n0 heads, 8-15 = n1 heads;
// 4 key MFMAs shared by both n, 2+2 edge MFMAs with half-zero A.
// Edge staging: global lane->chunk PERMUTATION (same 16 full lines per
// instruction) makes the LDS destination byte-linear in lane -> zero-conflict
// writes (512 contiguous B/instr) and zero-conflict b128 fragment reads
// (granule g = kk*64+lane holds edge[br][kk*32+q*8+j], lane=q*16+br).
// ---------------------------------------------------------------------------
__global__ __launch_bounds__(512, 4) void k_attn(
    const float* __restrict__ query, const float* __restrict__ Wq,
    const float* __restrict__ Wk,
    const float* __restrict__ edge,
    const u16* __restrict__ vP, const u16* __restrict__ keyF,
    const float* __restrict__ Wp, const float* __restrict__ bias,
    float* __restrict__ out)
{
    const int pr   = blockIdx.x;          // pair index: n0 = 2*pr
    const int idx0 = pr * 2;              // global row b*N + n0
    const int b    = pr >> 8;
    const int t    = threadIdx.x;
    const int lane = t & 63;
    const int wv   = t >> 6;              // 0..7

    __shared__ __attribute__((aligned(16))) float attn_s[2][H_][MP_]; // 33.0 KB
    __shared__ __attribute__((aligned(16))) u16 elds[8][2][1024];     // 32 KB
    __shared__ float mh_s[2][2][256];                                 // 4 KB
    __shared__ float part_s[2][2][OUT_];                              // 1 KB

    // prologue scratch overlaid on attn_s (dead until logits writes begin)
    float* Xq   = &attn_s[0][0][0];         // [2][128] query rows
    float* qh_s = Xq + 256;                 // [2][256] q-proj
    u16*  qE_l  = (u16*)(qh_s + 512);       // [2][1536] folded qE (bf16)

    // lane->chunk permutation for edge loads (float4 units within a tile):
    // iter i reads chunk base16 + i*4; instruction covers rows 0-15 x one
    // 64B column block = 16 full lines; LDS dest = i*512 + lane*8 bytes.
    const int base16 = ((lane >> 1) & 15) * 16 + ((lane >> 5) << 1) + (lane & 1);

    // ---- early edge prefetch: first tile per wave, both n ----
    const float* eb0 = edge + (size_t)idx0 * (M_ * DE_);
    const float* eb1 = eb0 + (M_ * DE_);
    float4 ef0[4], ef1[4];
    {
        const float4* tb0 = reinterpret_cast<const float4*>(eb0 + (size_t)wv * 1024);
        const float4* tb1 = reinterpret_cast<const float4*>(eb1 + (size_t)wv * 1024);
#pragma unroll
        for (int i = 0; i < 4; ++i) {
            ef0[i] = tb0[base16 + i * 4];
            ef1[i] = tb1[base16 + i * 4];
        }
    }

    // ---- prologue: qh = (query . Wq) * 1/sqrt(O) ----
    if (t < 64)
        reinterpret_cast<float4*>(Xq)[t] =
            reinterpret_cast<const float4*>(query + (size_t)idx0 * D_)[t];
    __syncthreads();
    {
        const int n = t >> 8, col = t & 255;
        const float* wcol = Wq + (col >> 5) * (D_ * O_) + (col & 31);
        const float* x = Xq + n * D_;
        float acc = 0.f;
        for (int k = 0; k < D_; k += 4) {
            const float4 xv = *reinterpret_cast<const float4*>(x + k);
            acc += xv.x * wcol[(k+0) * O_] + xv.y * wcol[(k+1) * O_]
                 + xv.z * wcol[(k+2) * O_] + xv.w * wcol[(k+3) * O_];
        }
        qh_s[n * 256 + col] = acc * 0.17677669529663687f;
    }
    __syncthreads();
    // ---- fold Wk: qE[n][hj] = sum_o qh[n][h*32+o] * Wk[hj][o] ----
#pragma unroll
    for (int s = 0; s < 3; ++s) {
        const int hj = t + 512 * s;       // 0..1535
        const int h  = hj / DKE_;
        float w[O_];
#pragma unroll
        for (int i = 0; i < O_ / 4; ++i) {
            const float4 x = reinterpret_cast<const float4*>(Wk + (size_t)hj * O_)[i];
            w[4*i] = x.x; w[4*i+1] = x.y; w[4*i+2] = x.z; w[4*i+3] = x.w;
        }
#pragma unroll
        for (int n = 0; n < 2; ++n) {
            const float* qrow = qh_s + n * 256 + h * O_;
            float a = 0.f;
#pragma unroll
            for (int i = 0; i < O_ / 4; ++i) {
                const float4 qx = *reinterpret_cast<const float4*>(qrow + 4*i);
                a += qx.x * w[4*i] + qx.y * w[4*i+1] + qx.z * w[4*i+2] + qx.w * w[4*i+3];
            }
            qE_l[n * 1536 + hj] = f2bf(a);
        }
    }
    __syncthreads();

    // ---- A fragments (packed 2n): rows 0-7 = n0 heads, 8-15 = n1 heads ----
    const int br = lane & 15;             // A row / C col (m)
    const int q  = lane >> 4;             // k-quad
    const int nsel = br >> 3, hsel = br & 7;
    bf16x8 afr_k[4], afr_e0[2], afr_e1[2];
    {
        const u16* ab = qE_l + nsel * 1536 + hsel * DKE_;
#pragma unroll
        for (int kk = 0; kk < 4; ++kk)
            afr_k[kk] = *reinterpret_cast<const bf16x8*>(ab + kk * 32 + q * 8);
        const bf16x8 ze = {0,0,0,0,0,0,0,0};
#pragma unroll
        for (int kk = 0; kk < 2; ++kk) {
            const bf16x8 fr = *reinterpret_cast<const bf16x8*>(ab + 128 + kk * 32 + q * 8);
            afr_e0[kk] = nsel ? ze : fr;
            afr_e1[kk] = nsel ? fr : ze;
        }
    }
    __syncthreads();   // qE_l alias region must be dead before attn_s writes

    const u16* kfb = keyF + (size_t)b * (32 * 4 * 64 * 8);

    // ---- logits: each wave 4 m-tiles, both n per tile ----
    for (int it = 0; it < 4; ++it) {
        const int tl = it * 8 + wv;
        // stage both edge tiles: byte-linear LDS writes (zero conflicts)
#pragma unroll
        for (int i = 0; i < 4; ++i) {
            uint2 p0, p1;
            p0.x = pk2bf(ef0[i].x, ef0[i].y); p0.y = pk2bf(ef0[i].z, ef0[i].w);
            p1.x = pk2bf(ef1[i].x, ef1[i].y); p1.y = pk2bf(ef1[i].z, ef1[i].w);
            *reinterpret_cast<uint2*>(&elds[wv][0][i * 256 + lane * 4]) = p0;
            *reinterpret_cast<uint2*>(&elds[wv][1][i * 256 + lane * 4]) = p1;
        }
        // prefetch next tile pair (same permuted-coalesced pattern)
        if (it < 3) {
            const float4* tb0 = reinterpret_cast<const float4*>(eb0 + (size_t)(tl + 8) * 1024);
            const float4* tb1 = reinterpret_cast<const float4*>(eb1 + (size_t)(tl + 8) * 1024);
#pragma unroll
            for (int i = 0; i < 4; ++i) {
                ef0[i] = tb0[base16 + i * 4];
                ef1[i] = tb1[base16 + i * 4];
            }
        }
        // key MFMAs: shared by both n (packed A)
        floatx4 acc = {0.f, 0.f, 0.f, 0.f};
        const u16* kf = kfb + (size_t)tl * 2048 + lane * 8;
#pragma unroll
        for (int kk = 0; kk < 4; ++kk) {
            const bf16x8 bfr = *reinterpret_cast<const bf16x8*>(kf + kk * 512);
            acc = __builtin_amdgcn_mfma_f32_16x16x32_bf16(afr_k[kk], bfr, acc, 0, 0, 0);
        }
        // edge MFMAs: granule-linear b128 reads (zero conflicts)
#pragma unroll
        for (int kk = 0; kk < 2; ++kk) {
            const bf16x8 b0 = *reinterpret_cast<const bf16x8*>(&elds[wv][0][(kk * 64 + lane) * 8]);
            acc = __builtin_amdgcn_mfma_f32_16x16x32_bf16(afr_e0[kk], b0, acc, 0, 0, 0);
        }
#pragma unroll
        for (int kk = 0; kk < 2; ++kk) {
            const bf16x8 b1 = *reinterpret_cast<const bf16x8*>(&elds[wv][1][(kk * 64 + lane) * 8]);
            acc = __builtin_amdgcn_mfma_f32_16x16x32_bf16(afr_e1[kk], b1, acc, 0, 0, 0);
        }
        // C: col=br (m), row=q*4+i -> n = row>>3, h = row&7. All lanes write.
#pragma unroll
        for (int i = 0; i < 4; ++i) {
            const int rr = q * 4 + i;
            attn_s[rr >> 3][rr & 7][tl * 16 + br] = acc[i];
        }
    }
    __syncthreads();

    // ---- softmax over m: 16 rows = (n,h), 32 lanes per row ----
    {
        const int r = t >> 5, ml = t & 31;
        const int n = r >> 3, h = r & 7;
        float mx = -3.4e38f;
#pragma unroll 2
        for (int j = 0; j < 16; ++j) mx = fmaxf(mx, attn_s[n][h][ml + 32 * j]);
#pragma unroll
        for (int mask = 16; mask >= 1; mask >>= 1) mx = fmaxf(mx, __shfl_xor(mx, mask, 64));
        float sum = 0.f;
#pragma unroll 2
        for (int j = 0; j < 16; ++j) {
            const int m = ml + 32 * j;
            const float p = __expf(attn_s[n][h][m] - mx);
            attn_s[n][h][m] = p;
            sum += p;
        }
#pragma unroll
        for (int mask = 16; mask >= 1; mask >>= 1) sum += __shfl_xor(sum, mask, 64);
        const float inv = 1.f / sum;
#pragma unroll 2
        for (int j = 0; j < 16; ++j) attn_s[n][h][ml + 32 * j] *= inv;
    }
    __syncthreads();

    // ---- PV: col tt=(h,o), m split in halves; one vP pass feeds BOTH n ----
    {
        const int tt = t & 255, half = t >> 8, hh = tt >> 5;
        const u16* vb = vP + (size_t)b * (64 * 256 * 8)
                      + ((size_t)(half * 32) * 256 + tt) * 8;
        const int mbase = half * 256;
        float a00 = 0.f, a01 = 0.f, a10 = 0.f, a11 = 0.f;
#pragma unroll 8
        for (int j = 0; j < 32; ++j) {
            const uint4 v4 = *reinterpret_cast<const uint4*>(vb + (size_t)j * 2048);
            const int m0 = mbase + j * 8;
            const float4 w00 = *reinterpret_cast<const float4*>(&attn_s[0][hh][m0]);
            const float4 w01 = *reinterpret_cast<const float4*>(&attn_s[0][hh][m0 + 4]);
            const float4 w10 = *reinterpret_cast<const float4*>(&attn_s[1][hh][m0]);
            const float4 w11 = *reinterpret_cast<const float4*>(&attn_s[1][hh][m0 + 4]);
            const float v0 = __uint_as_float(v4.x << 16);
            const float v1 = __uint_as_float(v4.x & 0xffff0000u);
            const float v2 = __uint_as_float(v4.y << 16);
            const float v3 = __uint_as_float(v4.y & 0xffff0000u);
            const float v4f = __uint_as_float(v4.z << 16);
            const float v5 = __uint_as_float(v4.z & 0xffff0000u);
            const float v6 = __uint_as_float(v4.w << 16);
            const float v7 = __uint_as_float(v4.w & 0xffff0000u);
            a00 += w00.x * v0 + w00.y * v1 + w00.z * v2 + w00.w * v3;
            a01 += w01.x * v4f + w01.y * v5 + w01.z * v6 + w01.w * v7;
            a10 += w10.x * v0 + w10.y * v1 + w10.z * v2 + w10.w * v3;
            a11 += w11.x * v4f + w11.y * v5 + w11.z * v6 + w11.w * v7;
        }
        mh_s[0][half][tt] = a00 + a01;
        mh_s[1][half][tt] = a10 + a11;
    }
    __syncthreads();

    // ---- out[n][c] = bias[c] + sum_j mh[n][j] * Wp[j*128 + c] ----
    {
        const int n = t >> 8, hseg = (t >> 7) & 1, c = t & 127;
        const int j0 = hseg * 128;
        float acc = 0.f;
#pragma unroll 8
        for (int jj = 0; jj < 128; ++jj) {
            const int j = j0 + jj;
            acc += (mh_s[n][0][j] + mh_s[n][1][j]) * Wp[(size_t)j * OUT_ + c];
        }
        part_s[n][hseg][c] = acc;
    }
    __syncthreads();
    if (t < 256) {
        const int n = t >> 7, c = t & 127;
        out[(size_t)(idx0 + n) * OUT_ + c] = part_s[n][0][c] + part_s[n][1][c] + bias[c];
    }
}

// ---------------------------------------------------------------------------
extern "C" void kernel_launch(void* const* d_in, const int* in_sizes, int n_in,
                              void* d_out, int out_size, void* d_ws, size_t ws_size,
                              hipStream_t stream)
{
    const float* query = (const float*)d_in[0];   // [B,N,128]
    const float* key   = (const float*)d_in[1];   // [B,M,128]
    const float* value = (const float*)d_in[2];   // [B,M,128]
    const float* edge  = (const float*)d_in[3];   // [B,N,M,64]
    const float* Wq    = (const float*)d_in[4];   // [8,128,32]
    const float* Wk    = (const float*)d_in[5];   // [8,192,32]
    const float* Wv    = (const float*)d_in[6];   // [8,128,32]
    const float* Wp    = (const float*)d_in[7];   // [8,32,128]
    const float* bias  = (const float*)d_in[8];   // [128]
    float* out = (float*)d_out;                   // [B,N,128] fp32

    u16* vP_ws = (u16*)d_ws;                                  // 2*64*256*8*2 = 512 KB
    u16* kF_ws = vP_ws + (size_t)B_ * 64 * 256 * 8;           // 2*32*4*64*8*2 = 256 KB

    k_proj<<<192, 256, 0, stream>>>(value, Wv, key, vP_ws, kF_ws);
    k_attn<<<512, 512, 0, stream>>>(query, Wq, Wk, edge, vP_ws, kF_ws, Wp, bias, out);
}